// Round 10
// baseline (13488.626 us; speedup 1.0000x reference)
//
#include <hip/hip_runtime.h>
#include <math.h>

#define SCALE_F 0.03125f   // 1/sqrt(1024)

// =====================================================================
// fp32 tiled GEMM: C[M,N] = A[M,K] @ (BT ? B[N,K]^T : B[K,N])
// EPI: 0 = none, 1 = silu
// =====================================================================
template<bool BT, int EPI>
__global__ __launch_bounds__(256) void gemm_nt(const float* __restrict__ A,
                                               const float* __restrict__ Bm,
                                               float* __restrict__ C,
                                               int M, int N, int K) {
  __shared__ float As[32][68];
  __shared__ float Bs[32][68];
  const int tid = threadIdx.x;
  const int n0 = blockIdx.x * 64;
  const int m0 = blockIdx.y * 64;
  const int i0 = (tid >> 4) * 4;
  const int j0 = (tid & 15) * 4;
  float acc[4][4] = {};

  for (int k0 = 0; k0 < K; k0 += 32) {
#pragma unroll
    for (int s = 0; s < 2; ++s) {
      int id = tid + 256 * s;
      int r = id >> 3, c4 = id & 7;
      float4 v = *(const float4*)&A[(size_t)(m0 + r) * K + k0 + c4 * 4];
      As[c4 * 4 + 0][r] = v.x; As[c4 * 4 + 1][r] = v.y;
      As[c4 * 4 + 2][r] = v.z; As[c4 * 4 + 3][r] = v.w;
    }
    if (BT) {
#pragma unroll
      for (int s = 0; s < 2; ++s) {
        int id = tid + 256 * s;
        int r = id >> 3, c4 = id & 7;
        float4 v = *(const float4*)&Bm[(size_t)(n0 + r) * K + k0 + c4 * 4];
        Bs[c4 * 4 + 0][r] = v.x; Bs[c4 * 4 + 1][r] = v.y;
        Bs[c4 * 4 + 2][r] = v.z; Bs[c4 * 4 + 3][r] = v.w;
      }
    } else {
#pragma unroll
      for (int s = 0; s < 2; ++s) {
        int id = tid + 256 * s;
        int kk = id >> 4, c4 = id & 15;
        float4 v = *(const float4*)&Bm[(size_t)(k0 + kk) * N + n0 + c4 * 4];
        *(float4*)&Bs[kk][c4 * 4] = v;
      }
    }
    __syncthreads();
#pragma unroll
    for (int kk = 0; kk < 32; ++kk) {
      float4 a = *(const float4*)&As[kk][i0];
      float4 b = *(const float4*)&Bs[kk][j0];
      float av[4] = {a.x, a.y, a.z, a.w};
      float bv[4] = {b.x, b.y, b.z, b.w};
#pragma unroll
      for (int ii = 0; ii < 4; ++ii)
#pragma unroll
        for (int jj = 0; jj < 4; ++jj)
          acc[ii][jj] = fmaf(av[ii], bv[jj], acc[ii][jj]);
    }
    __syncthreads();
  }

#pragma unroll
  for (int ii = 0; ii < 4; ++ii) {
    float4 v;
    float* vp = (float*)&v;
#pragma unroll
    for (int jj = 0; jj < 4; ++jj) {
      float x = acc[ii][jj];
      if (EPI == 1) x = x / (1.0f + __expf(-x));
      vp[jj] = x;
    }
    *(float4*)&C[(size_t)(m0 + i0 + ii) * N + n0 + j0] = v;
  }
}

// =====================================================================
// Tagged mailboxes: 8-byte (float value | 32-bit step tag), agent scope.
// ALL cross-wg data self-announces: no flags, no flag round trips.
// Consumer protocol: issue all loads in ONE parallel batch, then fix up
// only the stale elements individually (R8 lesson: never re-load the
// whole batch on a miss).
// =====================================================================
typedef unsigned long long u64;
__device__ __forceinline__ u64 ald64(const u64* p) {
  return __hip_atomic_load(p, __ATOMIC_RELAXED, __HIP_MEMORY_SCOPE_AGENT);
}
__device__ __forceinline__ void ast64(u64* p, u64 v) {
  __hip_atomic_store(p, v, __ATOMIC_RELAXED, __HIP_MEMORY_SCOPE_AGENT);
}
__device__ __forceinline__ u64 pk(float v, int j) {
  return ((u64)(unsigned)j << 32) | (u64)__float_as_uint(v);
}
__device__ __forceinline__ float lo(u64 u) { return __uint_as_float((unsigned)u); }
// per-element fixup: spins ONLY if this element is stale
__device__ __forceinline__ u64 fx(const u64* p, u64 u, unsigned tj) {
  while ((unsigned)(u >> 32) != tj) {
    __builtin_amdgcn_s_sleep(2);
    u = ald64(p);
  }
  return u;
}

// Rotated tape addressing.
#define TIDX(n, e) ((n) * 64 + (((e) + (n)) & 63))

// 64 named weight scalars/thread. HARD LESSONS: local arrays -> scratch;
// VGPR budget = 65536/block_size, immovable; 64 floats fits 128.
#define REP32(M) M(0) M(1) M(2) M(3) M(4) M(5) M(6) M(7) M(8) M(9) M(10) \
  M(11) M(12) M(13) M(14) M(15) M(16) M(17) M(18) M(19) M(20) M(21) M(22) \
  M(23) M(24) M(25) M(26) M(27) M(28) M(29) M(30) M(31)

#define RW(i) const float wh##i = Whp[32 * (i)]; \
              const float ww##i = Wwp[32 * (i)];
#define MVI(i) { float4 hh = ht4[cseg + 32 * (i)]; \
  ah0 = fmaf(wh##i, hh.x, ah0); ah1 = fmaf(wh##i, hh.y, ah1); \
  ah2 = fmaf(wh##i, hh.z, ah2); ah3 = fmaf(wh##i, hh.w, ah3); \
  aw0 = fmaf(ww##i, hh.x, aw0); aw1 = fmaf(ww##i, hh.y, aw1); \
  aw2 = fmaf(ww##i, hh.z, aw2); aw3 = fmaf(ww##i, hh.w, aw3); }

// =====================================================================
// Group-shared persistent scan: 256 wgs x 512 threads (1 wg/CU, 8 waves).
// 4 groups of 64 wgs; group g serves batches 4g..4g+3; wg = (b_loc, es)
// owns (bsel, e-slice es) and produces rows R0..R0+16 of BOTH mats for
// all 4 batches (64 weight floats/thread in named regs).
// All cross-wg data = (value|step) mailboxes; batch-issue + per-element
// fixup. Correctness of overwrites: a wg reaches its step-(j+1) publishes
// only through S0(j+1) (needs h(j+1) from all owners) -> owners passed
// S4(j) -> their S2(j) consumed hop2(j); transitive over the group, so
// nothing is overwritten before every reader consumed it (R7 lattice).
// Step (6 barriers, tape double-buffered, lerp values kept in regs):
//  S0 stage h (8 u64 batch + fixup -> h_t) + 2 ps + w0 wx/gate | B1
//  S1 ws-reduce; matvec; publish Rh/wv (cseg0) + qp (lane0/wave) | B2
//  S2 w0:wa | w1:wa+8qp fixup+q+attn->c,s2 | w2:wv fixup | w3:Rh fixup |B3
//  S3 gather from tape[cur] (+s2*wv) -> read_lds; lerp->tape[nxt], t regs
//     (last: break after lerp) | B4
//  S4 w0: h(j+1)=tanh(Rh+wx+read+b), h_own, publish h tag j+1, wx out |B5
//  S5 ps partials from h_own x t-regs -> publish tag j+1; cur^=1; loop
// =====================================================================
__global__ __launch_bounds__(512) void scan_kernel(
    const float* __restrict__ W_h, const float* __restrict__ W_wr,
    const float* __restrict__ b_h, const float* __restrict__ gate,
    float* __restrict__ wx,       // [B][T][D]; rows overwritten with h*gate
    u64* __restrict__ h2,         // [B][1024] h mailboxes
    u64* __restrict__ ps2,        // [B][16][64] score-partial mailboxes
    u64* __restrict__ Rh2,        // [B][1024]
    u64* __restrict__ wv2,        // [B][1024]
    u64* __restrict__ qp2,        // [B][512] per-wave q partials
    float* __restrict__ hfin,     // [B][1024] final h_work
    float* __restrict__ tape_out) // [B][64][1024]
{
  const int tid  = threadIdx.x;
  const int wg   = blockIdx.x;
  const int g    = wg >> 6;
  const int idx  = wg & 63;
  const int b_loc = idx >> 4;
  const int es   = idx & 15;
  const int gb   = g * 4;
  const int bsel = gb + b_loc;
  const int E0   = es * 64;
  const int R0   = es * 64 + b_loc * 16;
  const int w    = tid >> 6;
  const int lane = tid & 63;
  const int row  = tid >> 5;      // 0..15
  const int cseg = tid & 31;      // 32 col segments
  const int gr   = R0 + row;      // produced row (both mats)
  const int nwr  = tid >> 3;      // tape slot n
  const int ksb  = tid & 7;       // 8-elem e-block

  __shared__ float h_t[4096];       // batch-transposed h: slot d = 4 batches
  __shared__ float tape_l[2][4096]; // double-buffered rotated tape, 32 KB
  __shared__ float ws_lds[64], wa_lds[64], attn_lds[64];  // attn_lds = c[n]
  __shared__ float wv_lds[64], Rh_lds[64], h_own[64], read_lds[64];
  __shared__ float s2_lds;
  // Pad past 80 KB: exactly 1 wg/CU.
  __shared__ volatile float lds_pad[8192];
  lds_pad[tid] = 0.0f; lds_pad[tid + 4096] = 0.0f;

  // ---- weight preload: row gr of W_h AND W_wr, cols cseg+32i ----
  const float* Whp = W_h + (size_t)gr * 1024 + cseg;
  const float* Wwp = W_wr + (size_t)gr * 1024 + cseg;
  REP32(RW)

  const float4* ht4 = (const float4*)h_t;

  for (int i = tid; i < 4096; i += 512) {
    tape_l[0][i] = 0.0f;
    tape_l[1][i] = 0.0f;
  }

  float bh_r = 0.0f;
  if (w == 0) bh_r = b_h[E0 + lane];
  __syncthreads();

  // ---- prologue: h(1) = tanh(wx0 + b_h) tag 1; ps tag 1 (= 0) ----
  if (w == 0) {
    size_t xi = (size_t)bsel * 1048576 + E0 + lane;
    float hv = tanhf(wx[xi] + bh_r);
    h_own[lane] = hv;
    ast64(&h2[(size_t)bsel * 1024 + E0 + lane], pk(hv, 1));
    wx[xi] = hv * gate[xi];                 // output row 0
  }
  if (tid < 64) ast64(&ps2[(size_t)bsel * 1024 + es * 64 + tid], pk(0.0f, 1));
  __syncthreads();

  int cur = 0;
  float t0, t1, t2, t3, t4, t5, t6, t7;   // lerp values (regs, live to epilogue)

  for (int j = 1; j <= 1024; ++j) {
    const bool last = (j == 1024);
    const unsigned tj = (unsigned)j;

    // ---- w0: wx/gate prefetch (no deps) ----
    float wxv = 0.0f, gv = 0.0f;
    size_t xj = 0;
    if (w == 0 && !last) {
      xj  = (size_t)bsel * 1048576 + (size_t)j * 1024 + E0 + lane;
      wxv = wx[xj];
      gv  = gate[xj];
    }

    // ---- S0: stage h(j): 8 u64 parallel issue + per-elem fixup ----
    {
      const u64* hb = h2 + (size_t)gb * 1024;
      const u64 *pa0 = hb + 0 * 1024 + 2 * tid, *pa1 = hb + 0 * 1024 + 2 * tid + 1;
      const u64 *pb0 = hb + 1 * 1024 + 2 * tid, *pb1 = hb + 1 * 1024 + 2 * tid + 1;
      const u64 *pc0 = hb + 2 * 1024 + 2 * tid, *pc1 = hb + 2 * 1024 + 2 * tid + 1;
      const u64 *pd0 = hb + 3 * 1024 + 2 * tid, *pd1 = hb + 3 * 1024 + 2 * tid + 1;
      const u64 *pp0 = &ps2[(size_t)bsel * 1024 + (ksb * 2) * 64 + nwr];
      const u64 *pp1 = &ps2[(size_t)bsel * 1024 + (ksb * 2 + 1) * 64 + nwr];
      u64 a0 = ald64(pa0), a1 = ald64(pa1);
      u64 b0 = ald64(pb0), b1 = ald64(pb1);
      u64 c0 = ald64(pc0), c1 = ald64(pc1);
      u64 d0 = ald64(pd0), d1 = ald64(pd1);
      u64 u0 = ald64(pp0), u1 = ald64(pp1);
      a0 = fx(pa0, a0, tj); a1 = fx(pa1, a1, tj);
      b0 = fx(pb0, b0, tj); b1 = fx(pb1, b1, tj);
      c0 = fx(pc0, c0, tj); c1 = fx(pc1, c1, tj);
      d0 = fx(pd0, d0, tj); d1 = fx(pd1, d1, tj);
      u0 = fx(pp0, u0, tj); u1 = fx(pp1, u1, tj);
      ((float4*)h_t)[2 * tid]     = make_float4(lo(a0), lo(b0), lo(c0), lo(d0));
      ((float4*)h_t)[2 * tid + 1] = make_float4(lo(a1), lo(b1), lo(c1), lo(d1));
      // ws reduce input
      float s = lo(u0) + lo(u1);
      s += __shfl_xor(s, 1);
      s += __shfl_xor(s, 2);
      s += __shfl_xor(s, 4);
      if (ksb == 0) ws_lds[nwr] = s;
    }
    __syncthreads();   // B1

    // ---- S1: matvec; publish Rh/wv + per-wave qp (all tagged j) ----
    float ah0 = 0.0f, ah1 = 0.0f, ah2 = 0.0f, ah3 = 0.0f;
    float aw0 = 0.0f, aw1 = 0.0f, aw2 = 0.0f, aw3 = 0.0f;
    REP32(MVI)
#pragma unroll
    for (int m = 1; m < 32; m <<= 1) {
      ah0 += __shfl_xor(ah0, m); ah1 += __shfl_xor(ah1, m);
      ah2 += __shfl_xor(ah2, m); ah3 += __shfl_xor(ah3, m);
      aw0 += __shfl_xor(aw0, m); aw1 += __shfl_xor(aw1, m);
      aw2 += __shfl_xor(aw2, m); aw3 += __shfl_xor(aw3, m);
    }
    {  // per-wave qp partial: rows 2w,2w+1 combined via shfl 32
      float4 hrow = ht4[gr];
      float q0 = aw0 * hrow.x, q1 = aw1 * hrow.y;
      float q2 = aw2 * hrow.z, q3 = aw3 * hrow.w;
      q0 += __shfl_xor(q0, 32); q1 += __shfl_xor(q1, 32);
      q2 += __shfl_xor(q2, 32); q3 += __shfl_xor(q3, 32);
      if (lane == 0) {
        ast64(&qp2[(size_t)(gb + 0) * 512 + idx * 8 + w], pk(q0, j));
        ast64(&qp2[(size_t)(gb + 1) * 512 + idx * 8 + w], pk(q1, j));
        ast64(&qp2[(size_t)(gb + 2) * 512 + idx * 8 + w], pk(q2, j));
        ast64(&qp2[(size_t)(gb + 3) * 512 + idx * 8 + w], pk(q3, j));
      }
    }
    if (cseg == 0) {
      ast64(&Rh2[(size_t)(gb + 0) * 1024 + gr], pk(ah0, j));
      ast64(&Rh2[(size_t)(gb + 1) * 1024 + gr], pk(ah1, j));
      ast64(&Rh2[(size_t)(gb + 2) * 1024 + gr], pk(ah2, j));
      ast64(&Rh2[(size_t)(gb + 3) * 1024 + gr], pk(ah3, j));
      ast64(&wv2[(size_t)(gb + 0) * 1024 + gr], pk(aw0, j));
      ast64(&wv2[(size_t)(gb + 1) * 1024 + gr], pk(aw1, j));
      ast64(&wv2[(size_t)(gb + 2) * 1024 + gr], pk(aw2, j));
      ast64(&wv2[(size_t)(gb + 3) * 1024 + gr], pk(aw3, j));
    }
    __syncthreads();   // B2 (ws_lds visibility; stores self-announce)

    // ---- S2: w0 wa | w1 q+attn->c,s2 | w2 wv | w3 Rh ----
    if (w == 0) {
      float s = ws_lds[lane] * SCALE_F;
      float m = s;
#pragma unroll
      for (int off = 1; off < 64; off <<= 1) m = fmaxf(m, __shfl_xor(m, off));
      float ex = __expf(s - m);
      float sum = ex;
#pragma unroll
      for (int off = 1; off < 64; off <<= 1) sum += __shfl_xor(sum, off);
      wa_lds[lane] = ex / sum;
    } else if (w == 1) {
      if (!last) {
        float wsr = ws_lds[lane];
        float sm = wsr * SCALE_F;
        float m = sm;
#pragma unroll
        for (int off = 1; off < 64; off <<= 1) m = fmaxf(m, __shfl_xor(m, off));
        float ex = __expf(sm - m);
        float sum = ex;
#pragma unroll
        for (int off = 1; off < 64; off <<= 1) sum += __shfl_xor(sum, off);
        float wa_l = ex / sum;
        // 8 qp mailboxes: parallel issue + per-elem fixup
        const u64* qb = &qp2[(size_t)bsel * 512 + lane * 8];
        u64 q0 = ald64(qb + 0), q1 = ald64(qb + 1), q2 = ald64(qb + 2),
            q3 = ald64(qb + 3), q4 = ald64(qb + 4), q5 = ald64(qb + 5),
            q6 = ald64(qb + 6), q7 = ald64(qb + 7);
        q0 = fx(qb + 0, q0, tj); q1 = fx(qb + 1, q1, tj);
        q2 = fx(qb + 2, q2, tj); q3 = fx(qb + 3, q3, tj);
        q4 = fx(qb + 4, q4, tj); q5 = fx(qb + 5, q5, tj);
        q6 = fx(qb + 6, q6, tj); q7 = fx(qb + 7, q7, tj);
        float qv = lo(q0) + lo(q1) + lo(q2) + lo(q3) +
                   lo(q4) + lo(q5) + lo(q6) + lo(q7);
#pragma unroll
        for (int off = 1; off < 64; off <<= 1) qv += __shfl_xor(qv, off);
        float rs = fmaf(wa_l, qv - wsr, wsr) * SCALE_F;
        float m2 = rs;
#pragma unroll
        for (int off = 1; off < 64; off <<= 1) m2 = fmaxf(m2, __shfl_xor(m2, off));
        float ex2 = __expf(rs - m2);
        float sum2 = ex2;
#pragma unroll
        for (int off = 1; off < 64; off <<= 1) sum2 += __shfl_xor(sum2, off);
        float att = ex2 / sum2;
        attn_lds[lane] = att * (1.0f - wa_l);       // c[n]
        float s2 = att * wa_l;
#pragma unroll
        for (int off = 1; off < 64; off <<= 1) s2 += __shfl_xor(s2, off);
        if (lane == 0) s2_lds = s2;
      }
    } else if (w == 2) {
      const u64* p = &wv2[(size_t)bsel * 1024 + E0 + lane];
      u64 v = ald64(p);
      v = fx(p, v, tj);
      wv_lds[lane] = lo(v);
    } else if (w == 3) {
      const u64* p = &Rh2[(size_t)bsel * 1024 + E0 + lane];
      u64 v = ald64(p);
      v = fx(p, v, tj);
      Rh_lds[lane] = lo(v);
    }
    __syncthreads();   // B3

    // ---- S3: gather from tape[cur] + lerp -> tape[nxt] (t regs) ----
    const float* tp_cur = tape_l[cur];
    float* tp_nxt = tape_l[cur ^ 1];
    if (!last) {
      int ge = tid >> 3, gn = tid & 7;
      float gsum = 0.0f;
#pragma unroll
      for (int i = 0; i < 8; ++i) {
        int n = gn * 8 + i;
        gsum = fmaf(attn_lds[n], tp_cur[TIDX(n, ge)], gsum);
      }
      gsum += __shfl_xor(gsum, 1);
      gsum += __shfl_xor(gsum, 2);
      gsum += __shfl_xor(gsum, 4);
      if (gn == 0) read_lds[ge] = gsum + s2_lds * wv_lds[ge];
    }
    {
      float wa = wa_lds[nwr];
#define LERP(i, tr) { int e = ksb * 8 + (i); int ix = TIDX(nwr, e); \
      float tv = tp_cur[ix]; tv = fmaf(wa, wv_lds[e] - tv, tv); \
      tp_nxt[ix] = tv; tr = tv; }
      LERP(0, t0) LERP(1, t1) LERP(2, t2) LERP(3, t3)
      LERP(4, t4) LERP(5, t5) LERP(6, t6) LERP(7, t7)
#undef LERP
    }
    cur ^= 1;
    if (last) break;
    __syncthreads();   // B4

    // ---- S4: w0: h(j+1) = tanh(Rh + wx + read + b); publish tag j+1 ----
    if (w == 0) {
      float hv = tanhf(Rh_lds[lane] + wxv + read_lds[lane] + bh_r);
      h_own[lane] = hv;
      ast64(&h2[(size_t)bsel * 1024 + E0 + lane], pk(hv, j + 1));
      wx[xj] = hv * gv;
    }
    __syncthreads();   // B5

    // ---- S5: ps partials from h_own x t-regs -> publish tag j+1 ----
    {
      float s = t0 * h_own[ksb * 8 + 0] + t1 * h_own[ksb * 8 + 1] +
                t2 * h_own[ksb * 8 + 2] + t3 * h_own[ksb * 8 + 3] +
                t4 * h_own[ksb * 8 + 4] + t5 * h_own[ksb * 8 + 5] +
                t6 * h_own[ksb * 8 + 6] + t7 * h_own[ksb * 8 + 7];
      s += __shfl_xor(s, 1);
      s += __shfl_xor(s, 2);
      s += __shfl_xor(s, 4);
      if (ksb == 0)
        ast64(&ps2[(size_t)bsel * 1024 + es * 64 + nwr], pk(s, j + 1));
    }
    // no end barrier: next S0 writes h_t (last read before B2); tape[cur]
    // next touched after B3 of next step.
  }

  // ---- epilogue: final tape slice straight from t regs + final h ----
  {
    float* dst = &tape_out[(size_t)(bsel * 64 + nwr) * 1024 + E0];
    dst[ksb * 8 + 0] = t0; dst[ksb * 8 + 1] = t1;
    dst[ksb * 8 + 2] = t2; dst[ksb * 8 + 3] = t3;
    dst[ksb * 8 + 4] = t4; dst[ksb * 8 + 5] = t5;
    dst[ksb * 8 + 6] = t6; dst[ksb * 8 + 7] = t7;
  }
  if (w == 0) hfin[(size_t)bsel * 1024 + E0 + lane] = h_own[lane];
}

// =====================================================================
extern "C" void kernel_launch(void* const* d_in, const int* in_sizes, int n_in,
                              void* d_out, int out_size, void* d_ws, size_t ws_size,
                              hipStream_t stream) {
  (void)in_sizes; (void)n_in; (void)out_size; (void)ws_size;
  const float* x      = (const float*)d_in[0];
  const float* in_w   = (const float*)d_in[1];
  const float* out_w  = (const float*)d_in[2];
  const float* gate_w = (const float*)d_in[3];
  const float* W_x    = (const float*)d_in[4];
  const float* W_h    = (const float*)d_in[5];
  const float* W_wr   = (const float*)d_in[6];
  const float* b_h    = (const float*)d_in[7];

  float* out  = (float*)d_out;                     // [16][1024][1024]
  float* tape = out + (size_t)16 * 1024 * 1024;    // [16][64][1024]
  float* hfin = tape + (size_t)16 * 64 * 1024;     // [16][1024]

  float* ws = (float*)d_ws;
  // scan-time mailboxes overlay M1's region (M1 dead before scan)
  u64* h2  = (u64*)ws;                   // 16K pairs (32768 floats)
  u64* ps2 = (u64*)(ws + 32768);         // 16K pairs
  u64* Rh2 = (u64*)(ws + 65536);         // 16K pairs
  u64* wv2 = (u64*)(ws + 98304);         // 16K pairs
  u64* qp2 = (u64*)(ws + 131072);        // 8K pairs -> ends at 147456
  float* M1 = ws;                        // [1024][1024]
  float* wx = ws + (1 << 20);            // [16][1024][1024]

  float* gate = out;                     // park gate in d_out region

  dim3 blk(256);
  gemm_nt<false, 0><<<dim3(16, 16), blk, 0, stream>>>(W_x, in_w, M1, 1024, 1024, 1024);
  gemm_nt<true, 1><<<dim3(16, 256), blk, 0, stream>>>(x, gate_w, gate, 16384, 1024, 1024);
  gemm_nt<true, 0><<<dim3(16, 256), blk, 0, stream>>>(x, M1, wx, 16384, 1024, 1024);
  hipMemsetAsync(ws, 0, 147456 * sizeof(float), stream);   // zero tags
  scan_kernel<<<256, 512, 0, stream>>>(W_h, W_wr, b_h, gate, wx, h2, ps2,
                                       Rh2, wv2, qp2, hfin, tape);
  gemm_nt<true, 0><<<dim3(16, 256), blk, 0, stream>>>(wx, out_w, out, 16384, 1024, 1024);
}

// Round 11
// 11178.668 us; speedup vs baseline: 1.2066x; 1.2066x over previous
//
#include <hip/hip_runtime.h>
#include <math.h>

#define SCALE_F 0.03125f   // 1/sqrt(1024)

// =====================================================================
// fp32 tiled GEMM: C[M,N] = A[M,K] @ (BT ? B[N,K]^T : B[K,N])
// EPI: 0 = none, 1 = silu
// =====================================================================
template<bool BT, int EPI>
__global__ __launch_bounds__(256) void gemm_nt(const float* __restrict__ A,
                                               const float* __restrict__ Bm,
                                               float* __restrict__ C,
                                               int M, int N, int K) {
  __shared__ float As[32][68];
  __shared__ float Bs[32][68];
  const int tid = threadIdx.x;
  const int n0 = blockIdx.x * 64;
  const int m0 = blockIdx.y * 64;
  const int i0 = (tid >> 4) * 4;
  const int j0 = (tid & 15) * 4;
  float acc[4][4] = {};

  for (int k0 = 0; k0 < K; k0 += 32) {
#pragma unroll
    for (int s = 0; s < 2; ++s) {
      int id = tid + 256 * s;
      int r = id >> 3, c4 = id & 7;
      float4 v = *(const float4*)&A[(size_t)(m0 + r) * K + k0 + c4 * 4];
      As[c4 * 4 + 0][r] = v.x; As[c4 * 4 + 1][r] = v.y;
      As[c4 * 4 + 2][r] = v.z; As[c4 * 4 + 3][r] = v.w;
    }
    if (BT) {
#pragma unroll
      for (int s = 0; s < 2; ++s) {
        int id = tid + 256 * s;
        int r = id >> 3, c4 = id & 7;
        float4 v = *(const float4*)&Bm[(size_t)(n0 + r) * K + k0 + c4 * 4];
        Bs[c4 * 4 + 0][r] = v.x; Bs[c4 * 4 + 1][r] = v.y;
        Bs[c4 * 4 + 2][r] = v.z; Bs[c4 * 4 + 3][r] = v.w;
      }
    } else {
#pragma unroll
      for (int s = 0; s < 2; ++s) {
        int id = tid + 256 * s;
        int kk = id >> 4, c4 = id & 15;
        float4 v = *(const float4*)&Bm[(size_t)(k0 + kk) * N + n0 + c4 * 4];
        *(float4*)&Bs[kk][c4 * 4] = v;
      }
    }
    __syncthreads();
#pragma unroll
    for (int kk = 0; kk < 32; ++kk) {
      float4 a = *(const float4*)&As[kk][i0];
      float4 b = *(const float4*)&Bs[kk][j0];
      float av[4] = {a.x, a.y, a.z, a.w};
      float bv[4] = {b.x, b.y, b.z, b.w};
#pragma unroll
      for (int ii = 0; ii < 4; ++ii)
#pragma unroll
        for (int jj = 0; jj < 4; ++jj)
          acc[ii][jj] = fmaf(av[ii], bv[jj], acc[ii][jj]);
    }
    __syncthreads();
  }

#pragma unroll
  for (int ii = 0; ii < 4; ++ii) {
    float4 v;
    float* vp = (float*)&v;
#pragma unroll
    for (int jj = 0; jj < 4; ++jj) {
      float x = acc[ii][jj];
      if (EPI == 1) x = x / (1.0f + __expf(-x));
      vp[jj] = x;
    }
    *(float4*)&C[(size_t)(m0 + i0 + ii) * N + n0 + j0] = v;
  }
}

// =====================================================================
// Tagged mailboxes: 8-byte (float value | 32-bit step tag), agent scope.
// =====================================================================
typedef unsigned long long u64;
__device__ __forceinline__ u64 ald64(const u64* p) {
  return __hip_atomic_load(p, __ATOMIC_RELAXED, __HIP_MEMORY_SCOPE_AGENT);
}
__device__ __forceinline__ void ast64(u64* p, u64 v) {
  __hip_atomic_store(p, v, __ATOMIC_RELAXED, __HIP_MEMORY_SCOPE_AGENT);
}
__device__ __forceinline__ u64 pk(float v, int j) {
  return ((u64)(unsigned)j << 32) | (u64)__float_as_uint(v);
}
__device__ __forceinline__ float lo(u64 u) { return __uint_as_float((unsigned)u); }
__device__ __forceinline__ float pollv(const u64* p, int j) {
  u64 u = ald64(p);
  while ((unsigned)(u >> 32) != (unsigned)j) {
    __builtin_amdgcn_s_sleep(1);
    u = ald64(p);
  }
  return lo(u);
}
// per-element fixup: spins ONLY if this element is stale
__device__ __forceinline__ u64 fx(const u64* p, u64 u, unsigned tj) {
  while ((unsigned)(u >> 32) != tj) {
    __builtin_amdgcn_s_sleep(1);
    u = ald64(p);
  }
  return u;
}

// Rotated tape addressing.
#define TIDX(n, e) ((n) * 64 + (((e) + (n)) & 63))

// 64 named weight scalars/thread. HARD LESSONS: local arrays -> scratch;
// VGPR budget = 65536/block_size, immovable; 64 floats fits 128.
#define REP32(M) M(0) M(1) M(2) M(3) M(4) M(5) M(6) M(7) M(8) M(9) M(10) \
  M(11) M(12) M(13) M(14) M(15) M(16) M(17) M(18) M(19) M(20) M(21) M(22) \
  M(23) M(24) M(25) M(26) M(27) M(28) M(29) M(30) M(31)

#define RW(i) const float wh##i = Whp[32 * (i)]; \
              const float ww##i = Wwp[32 * (i)];
#define MVI(i) { float4 hh = ht4[cseg + 32 * (i)]; \
  ah0 = fmaf(wh##i, hh.x, ah0); ah1 = fmaf(wh##i, hh.y, ah1); \
  ah2 = fmaf(wh##i, hh.z, ah2); ah3 = fmaf(wh##i, hh.w, ah3); \
  aw0 = fmaf(ww##i, hh.x, aw0); aw1 = fmaf(ww##i, hh.y, aw1); \
  aw2 = fmaf(ww##i, hh.z, aw2); aw3 = fmaf(ww##i, hh.w, aw3); }

#define TAGOK(u) ((unsigned)((u) >> 32) == tj)

// =====================================================================
// Group-shared persistent scan: 256 wgs x 512 threads (1 wg/CU, 8 waves).
// XCD-CONFINED GROUPS: g = wg & 3, idx = wg >> 2. Under round-robin
// wg->XCD dispatch (XCD = wg % 8), group g's 64 wgs land on exactly 2
// XCDs {g, g+4} -> all group sync traffic stays within 2 L2 domains +
// LLC instead of spanning all 8 XCDs. (Pure index permutation: correct
// under ANY dispatch mapping.)
// Group g serves batches 4g..4g+3; wg = (b_loc = idx>>4, es = idx&15)
// owns (bsel, e-slice es) and produces rows R0..R0+16 of BOTH mats for
// all 4 batches (64 weight floats/thread in named regs).
// All cross-wg data = (value|step) mailboxes (R7 protocol). qp partials
// publish from S1 per-wave (shfl32) so they ride the same hop as Rh/wv.
// Overwrite safety: R7 transitive lattice (a wg reaches step-j+1
// publishes only through consumers of all step-j values).
// Step (6 barriers):
//  S0 stage h (batch-issue + per-elem fixup -> h_t float4) + 2 ps + ws
//     reduce + w0 wx/gate prefetch | B1
//  S1 matvec; publish Rh/wv (cseg0, FIRST) + qp (lane0/wave) | B2
//  S2 w0:wa | w1:wa+8 qp pollv+q+attn | w2:wv pollv | w3:Rh pollv | B3
//  S3 tape lerp | B4
//  S4 read gather from updated tape | B5
//  S5 w0: h(j+1)=tanh(Rh+wx+read+b) publish tag j+1, wx out | B6
//  S6 ps partials vs updated tape -> publish tag j+1; loop
// =====================================================================
__global__ __launch_bounds__(512) void scan_kernel(
    const float* __restrict__ W_h, const float* __restrict__ W_wr,
    const float* __restrict__ b_h, const float* __restrict__ gate,
    float* __restrict__ wx,       // [B][T][D]; rows overwritten with h*gate
    u64* __restrict__ h2,         // [B][1024] h mailboxes
    u64* __restrict__ ps2,        // [B][16][64] score-partial mailboxes
    u64* __restrict__ Rh2,        // [B][1024]
    u64* __restrict__ wv2,        // [B][1024]
    u64* __restrict__ qp2,        // [B][512] per-wave q partials
    float* __restrict__ hfin,     // [B][1024] final h_work
    float* __restrict__ tape_out) // [B][64][1024]
{
  const int tid  = threadIdx.x;
  const int wg   = blockIdx.x;
  const int g    = wg & 3;        // XCD-confined group
  const int idx  = wg >> 2;       // in-group index 0..63
  const int b_loc = idx >> 4;
  const int es   = idx & 15;
  const int gb   = g * 4;
  const int bsel = gb + b_loc;
  const int E0   = es * 64;
  const int R0   = es * 64 + b_loc * 16;
  const int w    = tid >> 6;
  const int lane = tid & 63;
  const int row  = tid >> 5;      // 0..15
  const int cseg = tid & 31;      // 32 col segments
  const int gr   = R0 + row;      // produced row (both mats)
  const int nwr  = tid >> 3;      // tape slot n
  const int ksb  = tid & 7;       // 8-elem e-block

  __shared__ float h_t[4096];       // batch-transposed h: h_t[4d+b], 16 KB
  __shared__ float tape_l[4096];    // rotated, 16 KB
  __shared__ float ws_lds[64], wa_lds[64], attn_lds[64];
  __shared__ float wv_lds[64], Rh_lds[64], h_own[64], read_lds[64];
  // Pad past 80 KB: exactly 1 wg/CU.
  __shared__ volatile float lds_pad[12288];
  lds_pad[tid] = 0.0f; lds_pad[tid + 512] = 0.0f;

  // ---- weight preload: row gr of W_h AND W_wr, cols cseg+32i ----
  const float* Whp = W_h + (size_t)gr * 1024 + cseg;
  const float* Wwp = W_wr + (size_t)gr * 1024 + cseg;
  REP32(RW)

  const float4* ht4 = (const float4*)h_t;

  for (int i = tid; i < 4096; i += 512) tape_l[i] = 0.0f;

  float bh_r = 0.0f;
  if (w == 0) bh_r = b_h[E0 + lane];
  __syncthreads();

  // ---- prologue: h(1) = tanh(wx0 + b_h) tag 1; ps tag 1 (= 0) ----
  if (w == 0) {
    size_t xi = (size_t)bsel * 1048576 + E0 + lane;
    float hv = tanhf(wx[xi] + bh_r);
    h_own[lane] = hv;
    ast64(&h2[(size_t)bsel * 1024 + E0 + lane], pk(hv, 1));
    wx[xi] = hv * gate[xi];                 // output row 0
  }
  if (tid < 64) ast64(&ps2[(size_t)bsel * 1024 + es * 64 + tid], pk(0.0f, 1));
  __syncthreads();

  for (int j = 1; j <= 1024; ++j) {
    const bool last = (j == 1024);
    const unsigned tj = (unsigned)j;

    // ---- w0: wx/gate prefetch (no deps) ----
    float wxv = 0.0f, gv = 0.0f;
    size_t xj = 0;
    if (w == 0 && !last) {
      xj  = (size_t)bsel * 1048576 + (size_t)j * 1024 + E0 + lane;
      wxv = wx[xj];
      gv  = gate[xj];
    }

    // ---- S0: stage h(j): batch issue + per-elem fixup; ps; ws ----
    {
      const u64* hb = h2 + (size_t)gb * 1024;
      const u64 *pa0 = hb + 0 * 1024 + 2 * tid, *pa1 = pa0 + 1;
      const u64 *pb0 = hb + 1 * 1024 + 2 * tid, *pb1 = pb0 + 1;
      const u64 *pc0 = hb + 2 * 1024 + 2 * tid, *pc1 = pc0 + 1;
      const u64 *pd0 = hb + 3 * 1024 + 2 * tid, *pd1 = pd0 + 1;
      const u64 *pp0 = &ps2[(size_t)bsel * 1024 + (ksb * 2) * 64 + nwr];
      const u64 *pp1 = &ps2[(size_t)bsel * 1024 + (ksb * 2 + 1) * 64 + nwr];
      u64 a0 = ald64(pa0), a1 = ald64(pa1);
      u64 b0 = ald64(pb0), b1 = ald64(pb1);
      u64 c0 = ald64(pc0), c1 = ald64(pc1);
      u64 d0 = ald64(pd0), d1 = ald64(pd1);
      u64 u0 = ald64(pp0), u1 = ald64(pp1);
      a0 = fx(pa0, a0, tj); a1 = fx(pa1, a1, tj);
      b0 = fx(pb0, b0, tj); b1 = fx(pb1, b1, tj);
      c0 = fx(pc0, c0, tj); c1 = fx(pc1, c1, tj);
      d0 = fx(pd0, d0, tj); d1 = fx(pd1, d1, tj);
      u0 = fx(pp0, u0, tj); u1 = fx(pp1, u1, tj);
      ((float4*)h_t)[2 * tid]     = make_float4(lo(a0), lo(b0), lo(c0), lo(d0));
      ((float4*)h_t)[2 * tid + 1] = make_float4(lo(a1), lo(b1), lo(c1), lo(d1));
      float s = lo(u0) + lo(u1);
      s += __shfl_xor(s, 1);
      s += __shfl_xor(s, 2);
      s += __shfl_xor(s, 4);
      if (ksb == 0) ws_lds[nwr] = s;
    }
    __syncthreads();   // B1

    // ---- S1: matvec; publish Rh/wv FIRST, then per-wave qp ----
    float ah0 = 0.0f, ah1 = 0.0f, ah2 = 0.0f, ah3 = 0.0f;
    float aw0 = 0.0f, aw1 = 0.0f, aw2 = 0.0f, aw3 = 0.0f;
    REP32(MVI)
#pragma unroll
    for (int m = 1; m < 32; m <<= 1) {
      ah0 += __shfl_xor(ah0, m); ah1 += __shfl_xor(ah1, m);
      ah2 += __shfl_xor(ah2, m); ah3 += __shfl_xor(ah3, m);
      aw0 += __shfl_xor(aw0, m); aw1 += __shfl_xor(aw1, m);
      aw2 += __shfl_xor(aw2, m); aw3 += __shfl_xor(aw3, m);
    }
    if (cseg == 0) {
      ast64(&Rh2[(size_t)(gb + 0) * 1024 + gr], pk(ah0, j));
      ast64(&Rh2[(size_t)(gb + 1) * 1024 + gr], pk(ah1, j));
      ast64(&Rh2[(size_t)(gb + 2) * 1024 + gr], pk(ah2, j));
      ast64(&Rh2[(size_t)(gb + 3) * 1024 + gr], pk(ah3, j));
      ast64(&wv2[(size_t)(gb + 0) * 1024 + gr], pk(aw0, j));
      ast64(&wv2[(size_t)(gb + 1) * 1024 + gr], pk(aw1, j));
      ast64(&wv2[(size_t)(gb + 2) * 1024 + gr], pk(aw2, j));
      ast64(&wv2[(size_t)(gb + 3) * 1024 + gr], pk(aw3, j));
    }
    {  // per-wave qp partial: rows 2w,2w+1 combined via shfl 32
      float4 hrow = ht4[gr];
      float q0 = aw0 * hrow.x, q1 = aw1 * hrow.y;
      float q2 = aw2 * hrow.z, q3 = aw3 * hrow.w;
      q0 += __shfl_xor(q0, 32); q1 += __shfl_xor(q1, 32);
      q2 += __shfl_xor(q2, 32); q3 += __shfl_xor(q3, 32);
      if (lane == 0) {
        ast64(&qp2[(size_t)(gb + 0) * 512 + idx * 8 + w], pk(q0, j));
        ast64(&qp2[(size_t)(gb + 1) * 512 + idx * 8 + w], pk(q1, j));
        ast64(&qp2[(size_t)(gb + 2) * 512 + idx * 8 + w], pk(q2, j));
        ast64(&qp2[(size_t)(gb + 3) * 512 + idx * 8 + w], pk(q3, j));
      }
    }
    __syncthreads();   // B2

    // ---- S2: w0 wa | w1 q+attn | w2 wv | w3 Rh ----
    if (w == 0) {
      float s = ws_lds[lane] * SCALE_F;
      float m = s;
#pragma unroll
      for (int off = 1; off < 64; off <<= 1) m = fmaxf(m, __shfl_xor(m, off));
      float ex = __expf(s - m);
      float sum = ex;
#pragma unroll
      for (int off = 1; off < 64; off <<= 1) sum += __shfl_xor(sum, off);
      wa_lds[lane] = ex / sum;
    } else if (w == 1) {
      if (!last) {
        // redundant own wa (keeps the chain wave-local)
        float wsr = ws_lds[lane];
        float sm = wsr * SCALE_F;
        float m = sm;
#pragma unroll
        for (int off = 1; off < 64; off <<= 1) m = fmaxf(m, __shfl_xor(m, off));
        float ex = __expf(sm - m);
        float sum = ex;
#pragma unroll
        for (int off = 1; off < 64; off <<= 1) sum += __shfl_xor(sum, off);
        float wa_l = ex / sum;
        // 8 qp mailboxes, sequential pollv (readiness-dominated anyway)
        const u64* qb = &qp2[(size_t)bsel * 512 + lane * 8];
        float qv = pollv(qb + 0, j) + pollv(qb + 1, j) +
                   pollv(qb + 2, j) + pollv(qb + 3, j) +
                   pollv(qb + 4, j) + pollv(qb + 5, j) +
                   pollv(qb + 6, j) + pollv(qb + 7, j);
#pragma unroll
        for (int off = 1; off < 64; off <<= 1) qv += __shfl_xor(qv, off);
        float rs = fmaf(wa_l, qv - wsr, wsr) * SCALE_F;
        float m2 = rs;
#pragma unroll
        for (int off = 1; off < 64; off <<= 1) m2 = fmaxf(m2, __shfl_xor(m2, off));
        float ex2 = __expf(rs - m2);
        float sum2 = ex2;
#pragma unroll
        for (int off = 1; off < 64; off <<= 1) sum2 += __shfl_xor(sum2, off);
        attn_lds[lane] = ex2 / sum2;
      }
    } else if (w == 2) {
      wv_lds[lane] = pollv(&wv2[(size_t)bsel * 1024 + E0 + lane], j);
    } else if (w == 3) {
      Rh_lds[lane] = pollv(&Rh2[(size_t)bsel * 1024 + E0 + lane], j);
    }
    __syncthreads();   // B3

    // ---- S3: tape lerp ----
    {
      float wa = wa_lds[nwr];
#pragma unroll
      for (int i = 0; i < 8; ++i) {
        int e = ksb * 8 + i;
        int ix = TIDX(nwr, e);
        float t = tape_l[ix];
        tape_l[ix] = fmaf(wa, wv_lds[e] - t, t);
      }
    }
    if (last) break;
    __syncthreads();   // B4

    // ---- S4: read gather: read[e] = sum_n attn[n]*tape[n][e] ----
    {
      int ge = tid >> 3, gn = tid & 7;
      float gsum = 0.0f;
#pragma unroll
      for (int i = 0; i < 8; ++i) {
        int n = gn * 8 + i;
        gsum = fmaf(attn_lds[n], tape_l[TIDX(n, ge)], gsum);
      }
      gsum += __shfl_xor(gsum, 1);
      gsum += __shfl_xor(gsum, 2);
      gsum += __shfl_xor(gsum, 4);
      if (gn == 0) read_lds[ge] = gsum;
    }
    __syncthreads();   // B5

    // ---- S5: h(j+1) = tanh(Rh + wx_j + read + b_h); publish tag j+1 ----
    if (w == 0) {
      float hv = tanhf(Rh_lds[lane] + wxv + read_lds[lane] + bh_r);
      h_own[lane] = hv;
      ast64(&h2[(size_t)bsel * 1024 + E0 + lane], pk(hv, j + 1));
      wx[xj] = hv * gv;
    }
    __syncthreads();   // B6

    // ---- S6: ps partials vs updated tape -> publish tag j+1 ----
    {
      float s = 0.0f;
#pragma unroll
      for (int i = 0; i < 8; ++i) {
        int e = ksb * 8 + i;
        s = fmaf(h_own[e], tape_l[TIDX(nwr, e)], s);
      }
      s += __shfl_xor(s, 1);
      s += __shfl_xor(s, 2);
      s += __shfl_xor(s, 4);
      if (ksb == 0)
        ast64(&ps2[(size_t)bsel * 1024 + es * 64 + nwr], pk(s, j + 1));
    }
    // no barrier: next S0 writes h_t only; B1 orders h_t vs S1 readers.
  }

  // ---- epilogue: final tape slice + final h_work ----
#pragma unroll
  for (int i = 0; i < 8; ++i) {
    int e = ksb * 8 + i;
    tape_out[(size_t)(bsel * 64 + nwr) * 1024 + E0 + e] = tape_l[TIDX(nwr, e)];
  }
  if (w == 0) hfin[(size_t)bsel * 1024 + E0 + lane] = h_own[lane];
}

// =====================================================================
extern "C" void kernel_launch(void* const* d_in, const int* in_sizes, int n_in,
                              void* d_out, int out_size, void* d_ws, size_t ws_size,
                              hipStream_t stream) {
  (void)in_sizes; (void)n_in; (void)out_size; (void)ws_size;
  const float* x      = (const float*)d_in[0];
  const float* in_w   = (const float*)d_in[1];
  const float* out_w  = (const float*)d_in[2];
  const float* gate_w = (const float*)d_in[3];
  const float* W_x    = (const float*)d_in[4];
  const float* W_h    = (const float*)d_in[5];
  const float* W_wr   = (const float*)d_in[6];
  const float* b_h    = (const float*)d_in[7];

  float* out  = (float*)d_out;                     // [16][1024][1024]
  float* tape = out + (size_t)16 * 1024 * 1024;    // [16][64][1024]
  float* hfin = tape + (size_t)16 * 64 * 1024;     // [16][1024]

  float* ws = (float*)d_ws;
  // scan-time mailboxes overlay M1's region (M1 dead before scan)
  u64* h2  = (u64*)ws;                   // 16K pairs (32768 floats)
  u64* ps2 = (u64*)(ws + 32768);         // 16K pairs
  u64* Rh2 = (u64*)(ws + 65536);         // 16K pairs
  u64* wv2 = (u64*)(ws + 98304);         // 16K pairs
  u64* qp2 = (u64*)(ws + 131072);        // 8K pairs -> ends at 147456
  float* M1 = ws;                        // [1024][1024]
  float* wx = ws + (1 << 20);            // [16][1024][1024]

  float* gate = out;                     // park gate in d_out region

  dim3 blk(256);
  gemm_nt<false, 0><<<dim3(16, 16), blk, 0, stream>>>(W_x, in_w, M1, 1024, 1024, 1024);
  gemm_nt<true, 1><<<dim3(16, 256), blk, 0, stream>>>(x, gate_w, gate, 16384, 1024, 1024);
  gemm_nt<true, 0><<<dim3(16, 256), blk, 0, stream>>>(x, M1, wx, 16384, 1024, 1024);
  hipMemsetAsync(ws, 0, 147456 * sizeof(float), stream);   // zero tags
  scan_kernel<<<256, 512, 0, stream>>>(W_h, W_wr, b_h, gate, wx, h2, ps2,
                                       Rh2, wv2, qp2, hfin, tape);
  gemm_nt<true, 0><<<dim3(16, 256), blk, 0, stream>>>(wx, out_w, out, 16384, 1024, 1024);
}